// Round 13
// baseline (177.472 us; speedup 1.0000x reference)
//
#include <hip/hip_runtime.h>
#include <hip/hip_bf16.h>
#include <math.h>

// ---------- types ----------
typedef __bf16 bf16x8 __attribute__((ext_vector_type(8)));
typedef float  floatx4 __attribute__((ext_vector_type(4)));
typedef float  floatx16 __attribute__((ext_vector_type(16)));
typedef unsigned u32x2 __attribute__((ext_vector_type(2)));

#define MFMA(a, b, c)   __builtin_amdgcn_mfma_f32_16x16x32_bf16((a), (b), (c), 0, 0, 0)
#define MFMA32(a, b, c) __builtin_amdgcn_mfma_f32_32x32x16_bf16((a), (b), (c), 0, 0, 0)

__device__ __forceinline__ unsigned short f2bf(float f) {
  union { float f; unsigned u; } v; v.f = f;
  unsigned r = v.u + 0x7FFFu + ((v.u >> 16) & 1u);
  return (unsigned short)(r >> 16);
}
__device__ __forceinline__ float bf2f(unsigned short u) {
  union { unsigned u; float f; } v; v.u = ((unsigned)u) << 16;
  return v.f;
}
// pack two f32 -> one dword of 2 bf16 (RNE); compiler emits v_cvt_pk_bf16_f32
__device__ __forceinline__ unsigned pack2(float a, float b) {
  __bf16 x = (__bf16)a, y = (__bf16)b;
  unsigned short ux = __builtin_bit_cast(unsigned short, x);
  unsigned short uy = __builtin_bit_cast(unsigned short, y);
  return (unsigned)ux | ((unsigned)uy << 16);
}
__device__ __forceinline__ float exp2_fast(float x) {
#if __has_builtin(__builtin_amdgcn_exp2f)
  return __builtin_amdgcn_exp2f(x);
#else
  return exp2f(x);
#endif
}

// B=4, C=256, N=4096, Ci=32, SPLITS=4
// ---------- K_wconv: Wall[320][256] bf16 = [Wq;Wk;Wv] ----------
__global__ __launch_bounds__(256) void k_wconv(const float* __restrict__ Wq,
                                               const float* __restrict__ Wk,
                                               const float* __restrict__ Wv,
                                               unsigned short* __restrict__ Wall) {
  int i = blockIdx.x * 256 + threadIdx.x;
  int o = i >> 8, c = i & 255;
  float v = (o < 32) ? Wq[o * 256 + c]
          : (o < 64) ? Wk[(o - 32) * 256 + c]
                     : Wv[(o - 64) * 256 + c];
  Wall[i] = f2bf(v);
}

// ---------- K_projx: FUSED xpose+proj. 1024 blocks x 4 waves. ----------
// Block (b, m0): reads x[b][0..255][m0..m0+15] fp32 directly, converts to bf16,
// LDS-transposes to [n][c]; wave qr computes quarter = 1 qk tile + 4 v tiles.
// Outputs (fragment-linear for k_attn):
//   qbf[b][qblk128][kh2][hi2][q32][8ch]   (q pre-scaled by log2e, bias folded)
//   kbf[b][tile128][kh2][hi2][key32][8ch]
//   vbf[b][kb128][cb8][kk2][hi2][ch32][8key]
__global__ __launch_bounds__(256) void k_projx(const float* __restrict__ x,
                                               const unsigned short* __restrict__ Wall,
                                               const float* __restrict__ bq,
                                               const float* __restrict__ bk,
                                               const float* __restrict__ bv,
                                               unsigned short* __restrict__ qbf,
                                               unsigned short* __restrict__ kbf,
                                               unsigned short* __restrict__ vbf) {
  int b = blockIdx.x >> 8;
  int m0 = (blockIdx.x & 255) * 16;
  int tid = threadIdx.x;
  int qr = tid >> 6;                // wave id = quarter
  int lane = tid & 63;
  int l15 = lane & 15, quad = lane >> 4;

  // xs[n][c] bf16, row stride 264 shorts (16B-aligned, bank-spread)
  __shared__ alignas(16) unsigned short xs[16][264];
  __shared__ alignas(16) unsigned short Os[4][64][24];

  // ---- stage x -> LDS (thread t owns channel c=t; reads its full 64B line) ----
  {
    const float* xrow = x + ((size_t)b * 256 + tid) * 4096 + m0;
#pragma unroll
    for (int g = 0; g < 4; ++g) {
      float4 d = *(const float4*)(xrow + g * 4);
      xs[g * 4 + 0][tid] = f2bf(d.x);
      xs[g * 4 + 1][tid] = f2bf(d.y);
      xs[g * 4 + 2][tid] = f2bf(d.z);
      xs[g * 4 + 3][tid] = f2bf(d.w);
    }
  }
  __syncthreads();

  // ---- MFMA: 8 ks-steps x (1 qk tile + 4 v tiles) for this wave's quarter ----
  floatx4 acc[5];
#pragma unroll
  for (int tt = 0; tt < 5; ++tt) acc[tt] = floatx4{0.f, 0.f, 0.f, 0.f};

#pragma unroll
  for (int ks = 0; ks < 8; ++ks) {
    bf16x8 a = *(const bf16x8*)&xs[l15][ks * 32 + quad * 8];
    {
      bf16x8 w = *(const bf16x8*)(Wall + (size_t)(qr * 16 + l15) * 256 + ks * 32 + quad * 8);
      acc[0] = MFMA(a, w, acc[0]);
    }
#pragma unroll
    for (int t = 0; t < 4; ++t) {
      int gt = 4 + qr * 4 + t;
      bf16x8 w = *(const bf16x8*)(Wall + (size_t)(gt * 16 + l15) * 256 + ks * 32 + quad * 8);
      acc[1 + t] = MFMA(a, w, acc[1 + t]);
    }
  }
  // qk tile: o = qr*16 + l15; q (o<32, scaled by log2e) or k. Fragment-linear stores.
  {
    int o = qr * 16 + l15;
    float bias = (o < 32) ? bq[o] : bk[o - 32];
    float scale = (o < 32) ? 1.44269504088896340736f : 1.0f;
    unsigned short* dst = (o < 32) ? qbf : kbf;
    int oc = o & 31;
    int kh = oc >> 4, h2 = (oc >> 3) & 1, c8 = oc & 7;
#pragma unroll
    for (int r = 0; r < 4; ++r) {
      int m = m0 + quad * 4 + r;
      dst[(size_t)b * 131072 + (size_t)(m >> 5) * 1024 + kh * 512 + h2 * 256 +
          (m & 31) * 8 + c8] = f2bf((acc[0][r] + bias) * scale);
    }
  }
  // v tiles (4 -> 64 channels): LDS transpose then fragment-linear stores
#pragma unroll
  for (int t = 0; t < 4; ++t) {
    int lr = t * 16 + l15;                  // local channel 0..63
    int c = qr * 64 + lr;                   // global v channel
    float bias = bv[c];
#pragma unroll
    for (int r = 0; r < 4; ++r)
      Os[qr][lr][quad * 4 + r] = f2bf(acc[1 + t][r] + bias);
  }
  __syncthreads();
  {
    int kb = m0 >> 5, kk = (m0 >> 4) & 1;   // this block's 16 keys = one kk-half
#pragma unroll
    for (int i = 0; i < 2; ++i) {
      int idx = lane + 64 * i;              // 128 granules of 16B per wave
      int r = idx >> 1, g = idx & 1;        // r = local ch 0..63, g = key-half
      int c = qr * 64 + r;
      int cb = c >> 5, ch = c & 31;
      *(uint4*)(vbf + (size_t)b * 1048576 + (size_t)kb * 8192 +
                (size_t)cb * 1024 + kk * 512 + g * 256 + ch * 8) =
          *(const uint4*)&Os[qr][r][g * 8];
    }
  }
}

// ---------- softmax helper: st (16 f32, S^T tile) -> l partial + PV A-fragments ----------
// st reg r holds S^T[key=(r&3)+8*(r>>2)+4*hi][q=lane&31] (32x32 C/D layout).
// S was pre-scaled by log2e (folded into Q), so exp(S) == exp2(st).
// pa[ks] must hold P[q=lane&31][key=16*ks+8*hi+j], j=0..7 (32x32 A-operand layout).
__device__ __forceinline__ void softmax_pack(floatx16 st, float& lp, bf16x8 (&pa)[2], int hi) {
  float p[16];
#pragma unroll
  for (int r = 0; r < 16; ++r) p[r] = exp2_fast(st[r]);
  lp += (((p[0] + p[1]) + (p[2] + p[3])) + ((p[4] + p[5]) + (p[6] + p[7]))) +
        (((p[8] + p[9]) + (p[10] + p[11])) + ((p[12] + p[13]) + (p[14] + p[15])));
  unsigned d0[4], d1[4];
#pragma unroll
  for (int t = 0; t < 4; ++t) {
    d0[t] = pack2(p[4 * t + 0], p[4 * t + 1]);   // keys r=0,1 of subtile t (own hi)
    d1[t] = pack2(p[4 * t + 2], p[4 * t + 3]);   // keys r=2,3
  }
#pragma unroll
  for (int ks = 0; ks < 2; ++ks) {
#if __has_builtin(__builtin_amdgcn_permlane32_swap)
    (void)hi;
    u32x2 r0 = __builtin_amdgcn_permlane32_swap(d0[2 * ks], d0[2 * ks + 1], false, false);
    u32x2 r1 = __builtin_amdgcn_permlane32_swap(d1[2 * ks], d1[2 * ks + 1], false, false);
    union { unsigned u[4]; bf16x8 v; } u;
    u.u[0] = r0[0]; u.u[1] = r1[0]; u.u[2] = r0[1]; u.u[3] = r1[1];
    pa[ks] = u.v;
#else
    unsigned s0 = hi ? d0[2 * ks] : d0[2 * ks + 1];
    unsigned s1 = hi ? d1[2 * ks] : d1[2 * ks + 1];
    unsigned o0 = (unsigned)__shfl_xor((int)s0, 32);
    unsigned o1 = (unsigned)__shfl_xor((int)s1, 32);
    union { unsigned u[4]; bf16x8 v; } u;
    u.u[0] = hi ? o0 : d0[2 * ks];
    u.u[1] = hi ? o1 : d1[2 * ks];
    u.u[2] = hi ? d0[2 * ks + 1] : o0;
    u.u[3] = hi ? d1[2 * ks + 1] : o1;
    pa[ks] = u.v;
#endif
  }
}

// ---------- K_attn v10: 32q x 64ch waves for 4 waves/SIMD + fused merge epilogue ----
// Wave = (split s) x 32 queries x 64 channels: acc = 32 AGPR, ~123 total regs ->
// 4 waves/SIMD (2x the TLP of the 64qx128ch tile, which was pool-capped at 2).
// Round-7's failure modes fixed: epilogue is block-contiguous (no partial-line
// writes); V traffic only 2x v9 (L2-resident, ~16 TB/s << 34.5 ceiling).
// Block = 4 waves (splits) at fixed (b, qb, cz); fused cross-split reduce + out.
// grid = 2048 = b(4) x cz(4) x qb(128); XCD-swizzled: per-XCD = 2 (b,cz) V-slices (1MB).
__global__ __launch_bounds__(256, 4) void k_attn(const unsigned short* __restrict__ qbf,
                                                 const unsigned short* __restrict__ kbf,
                                                 const unsigned short* __restrict__ vbf,
                                                 const float* __restrict__ x,
                                                 const float* __restrict__ gma,
                                                 float* __restrict__ out) {
  // XCD swizzle: nwg=2048, 8 XCDs -> XCD x owns decoded range [x*256, x*256+256)
  int wg = (blockIdx.x & 7) * 256 + (blockIdx.x >> 3);
  const int qb = wg & 127;
  const int g  = wg >> 7;                   // 0..15 = b(4) x cz(4)
  const int cz = g & 3;                     // 64-channel quarter
  const int b  = g >> 2;
  const int s  = threadIdx.x >> 6;          // wave id = key-split
  const int lane = threadIdx.x & 63;
  const int l31 = lane & 31;
  const int hi  = lane >> 5;
  const int q0  = qb * 32;

  __shared__ float lpL[4][32];
  __shared__ float ltot[32];
  __shared__ alignas(16) unsigned short Ol[4][64][40];   // [split][ch][q, 80B rows]

  const floatx16 z16 = {0.f, 0.f, 0.f, 0.f, 0.f, 0.f, 0.f, 0.f,
                        0.f, 0.f, 0.f, 0.f, 0.f, 0.f, 0.f, 0.f};

  // Q fragments (B-operand: col = query l31, row ch = kh*16 + hi*8 + j), hoisted.
  bf16x8 qf[2];
  {
    const unsigned short* qbase =
        qbf + (size_t)b * 131072 + (size_t)qb * 1024 + hi * 256 + l31 * 8;
    qf[0] = *(const bf16x8*)(qbase);
    qf[1] = *(const bf16x8*)(qbase + 512);
  }

  floatx16 acc[2];
  acc[0] = z16; acc[1] = z16;

  float lp = 0.f;

  // K fragment base (A-operand: row = key l31, ch = kh*16 + hi*8 + j)
  const unsigned short* krow =
      kbf + (size_t)b * 131072 + (size_t)(s * 32) * 1024 + hi * 256 + l31 * 8;
  // V fragment base (B-operand: col = channel l31, key = kk*16 + hi*8 + j);
  // this wave's channels = cz*64 .. cz*64+63 = cb in {cz*2, cz*2+1}
  const unsigned short* vrow =
      vbf + (size_t)b * 1048576 + (size_t)(s * 32) * 8192 + (size_t)(cz * 2) * 1024 +
      hi * 256 + l31 * 8;

  bf16x8 kf0 = *(const bf16x8*)krow;
  bf16x8 kf1 = *(const bf16x8*)(krow + 512);

  for (int it = 0; it < 32; ++it) {
    // ---- V loads first (4 x 1KB contiguous): consumed at PV, ST+softmax cover latency
    bf16x8 vb[2][2];
    const unsigned short* vit = vrow + (size_t)it * 8192;
#pragma unroll
    for (int ct = 0; ct < 2; ++ct) {
      vb[ct][0] = *(const bf16x8*)(vit + ct * 1024);
      vb[ct][1] = *(const bf16x8*)(vit + ct * 1024 + 512);
    }

    // ---- S^T: mfma(K, Q) -> col = query (in-lane P rows); one 32x32 tile ----
    floatx16 st = MFMA32(kf0, qf[0], z16);
    st = MFMA32(kf1, qf[1], st);

    // ---- K prefetch for next iter (wrapped index keeps the last dead load in-region)
    const unsigned short* kn = krow + (size_t)((it + 1) & 31) * 1024;
    kf0 = *(const bf16x8*)kn;
    kf1 = *(const bf16x8*)(kn + 512);

    // ---- in-register softmax -> PV A-fragments (raw exp2, scale pre-folded) ----
    bf16x8 pa[2];
    softmax_pack(st, lp, pa, hi);

    // ---- PV: 4 MFMAs across the 2 channel-tiles ----
    __builtin_amdgcn_s_setprio(1);
#pragma unroll
    for (int ct = 0; ct < 2; ++ct) {
      acc[ct] = MFMA32(pa[0], vb[ct][0], acc[ct]);
      acc[ct] = MFMA32(pa[1], vb[ct][1], acc[ct]);
    }
    __builtin_amdgcn_s_setprio(0);
  }

  // ---- fused cross-split reduction + normalize + residual epilogue ----
  // lp: lane (l31,hi) holds query l31's partial over its hi key-subset; xor-32
  // completes the per-split row sum.
  lp += __shfl_xor(lp, 32);
  if (hi == 0) lpL[s][l31] = lp;

  // acc reg r of the 32x32 tile: query (r&3)+8*(r>>2)+4*hi, channel = ct*32+l31.
#pragma unroll
  for (int ct = 0; ct < 2; ++ct) {
#pragma unroll
    for (int gi = 0; gi < 4; ++gi) {
      unsigned w0 = pack2(acc[ct][4 * gi + 0], acc[ct][4 * gi + 1]);
      unsigned w1 = pack2(acc[ct][4 * gi + 2], acc[ct][4 * gi + 3]);
      unsigned long long w = (unsigned long long)w0 | ((unsigned long long)w1 << 32);
      *(unsigned long long*)&Ol[s][ct * 32 + l31][8 * gi + 4 * hi] = w;
    }
  }
  __syncthreads();
  if (threadIdx.x < 32) {
    int q = threadIdx.x;
    ltot[q] = (lpL[0][q] + lpL[1][q]) + (lpL[2][q] + lpL[3][q]);
  }
  __syncthreads();

  // merge: thread t -> ch = t>>2 (0..63), qg = t&3 (8 queries each).
  {
    const float gv = gma[0];
    int ch = threadIdx.x >> 2;
    int qg = threadIdx.x & 3;
    float o[8];
#pragma unroll
    for (int j = 0; j < 8; ++j) o[j] = 0.f;
#pragma unroll
    for (int sp = 0; sp < 4; ++sp) {
      uint4 a0 = *(const uint4*)&Ol[sp][ch][qg * 8];
      unsigned uu[4] = {a0.x, a0.y, a0.z, a0.w};
#pragma unroll
      for (int jj = 0; jj < 4; ++jj) {
        o[2 * jj + 0] += bf2f((unsigned short)(uu[jj] & 0xffffu));
        o[2 * jj + 1] += bf2f((unsigned short)(uu[jj] >> 16));
      }
    }
    size_t rowa = ((size_t)b * 256 + cz * 64 + ch) * 4096 + q0 + qg * 8;
    const float* xrow = x + rowa;
    float* orow = out + rowa;
#pragma unroll
    for (int j4 = 0; j4 < 2; ++j4) {
      float4 xv = *(const float4*)(xrow + j4 * 4);
      float4 r;
      r.x = xv.x + gv * o[j4 * 4 + 0] / ltot[qg * 8 + j4 * 4 + 0];
      r.y = xv.y + gv * o[j4 * 4 + 1] / ltot[qg * 8 + j4 * 4 + 1];
      r.z = xv.z + gv * o[j4 * 4 + 2] / ltot[qg * 8 + j4 * 4 + 2];
      r.w = xv.w + gv * o[j4 * 4 + 3] / ltot[qg * 8 + j4 * 4 + 3];
      *(float4*)(orow + j4 * 4) = r;
    }
  }
}

// ---------- launch ----------
extern "C" void kernel_launch(void* const* d_in, const int* in_sizes, int n_in,
                              void* d_out, int out_size, void* d_ws, size_t ws_size,
                              hipStream_t stream) {
  const float* x   = (const float*)d_in[0];
  const float* Wq  = (const float*)d_in[1];
  const float* bq  = (const float*)d_in[2];
  const float* Wk  = (const float*)d_in[3];
  const float* bk  = (const float*)d_in[4];
  const float* Wv  = (const float*)d_in[5];
  const float* bv  = (const float*)d_in[6];
  const float* gma = (const float*)d_in[7];
  float* out = (float*)d_out;

  // layout: [qbf][kbf][vbf][Wall]
  unsigned short* qbf  = (unsigned short*)d_ws;              // [4][128][2][2][32][8]
  unsigned short* kbf  = qbf + (size_t)4 * 131072;           // [4][128][2][2][32][8]
  unsigned short* vbf  = kbf + (size_t)4 * 131072;           // [4][128][8][2][2][32][8]
  unsigned short* Wall = vbf + (size_t)4 * 1048576;          // [320][256]

  k_wconv<<<320, 256, 0, stream>>>(Wq, Wk, Wv, Wall);
  k_projx<<<1024, 256, 0, stream>>>(x, Wall, bq, bk, bv, qbf, kbf, vbf);
  k_attn<<<2048, 256, 0, stream>>>(qbf, kbf, vbf, x, gma, out);
}

// Round 14
// 155.828 us; speedup vs baseline: 1.1389x; 1.1389x over previous
//
#include <hip/hip_runtime.h>
#include <hip/hip_bf16.h>
#include <math.h>

// ---------- types ----------
typedef __bf16 bf16x8 __attribute__((ext_vector_type(8)));
typedef float  floatx4 __attribute__((ext_vector_type(4)));
typedef float  floatx16 __attribute__((ext_vector_type(16)));
typedef unsigned u32x2 __attribute__((ext_vector_type(2)));

#define MFMA(a, b, c)   __builtin_amdgcn_mfma_f32_16x16x32_bf16((a), (b), (c), 0, 0, 0)
#define MFMA32(a, b, c) __builtin_amdgcn_mfma_f32_32x32x16_bf16((a), (b), (c), 0, 0, 0)

__device__ __forceinline__ unsigned short f2bf(float f) {
  union { float f; unsigned u; } v; v.f = f;
  unsigned r = v.u + 0x7FFFu + ((v.u >> 16) & 1u);
  return (unsigned short)(r >> 16);
}
__device__ __forceinline__ float bf2f(unsigned short u) {
  union { unsigned u; float f; } v; v.u = ((unsigned)u) << 16;
  return v.f;
}
// pack two f32 -> one dword of 2 bf16 (RNE); compiler emits v_cvt_pk_bf16_f32
__device__ __forceinline__ unsigned pack2(float a, float b) {
  __bf16 x = (__bf16)a, y = (__bf16)b;
  unsigned short ux = __builtin_bit_cast(unsigned short, x);
  unsigned short uy = __builtin_bit_cast(unsigned short, y);
  return (unsigned)ux | ((unsigned)uy << 16);
}
__device__ __forceinline__ float exp2_fast(float x) {
#if __has_builtin(__builtin_amdgcn_exp2f)
  return __builtin_amdgcn_exp2f(x);
#else
  return exp2f(x);
#endif
}

// B=4, C=256, N=4096, Ci=32, SPLITS=4
// ---------- K_wconv: Wall[320][256] bf16 = [Wq;Wk;Wv] ----------
__global__ __launch_bounds__(256) void k_wconv(const float* __restrict__ Wq,
                                               const float* __restrict__ Wk,
                                               const float* __restrict__ Wv,
                                               unsigned short* __restrict__ Wall) {
  int i = blockIdx.x * 256 + threadIdx.x;
  int o = i >> 8, c = i & 255;
  float v = (o < 32) ? Wq[o * 256 + c]
          : (o < 64) ? Wk[(o - 32) * 256 + c]
                     : Wv[(o - 64) * 256 + c];
  Wall[i] = f2bf(v);
}

// ---------- K_projx v2: coalesced x reads. 512 blocks x 4 waves. ----------
// Block (b, nb): reads x[b][0..255][n0..n0+31] fp32 with 8-threads-per-row mapping
// (wave touches 8 lines/instr instead of 64), converts to bf16 in LDS [32n][c];
// wave qr computes its quarter (1 qk tile + 4 v tiles) for both 16-n subtiles.
// Outputs (fragment-linear for k_attn, identical layouts to previous rounds):
//   qbf[b][qblk128][kh2][hi2][q32][8ch]   (q pre-scaled by log2e, bias folded)
//   kbf[b][tile128][kh2][hi2][key32][8ch]
//   vbf[b][kb128][cb8][kk2][hi2][ch32][8key]
__global__ __launch_bounds__(256) void k_projx(const float* __restrict__ x,
                                               const unsigned short* __restrict__ Wall,
                                               const float* __restrict__ bq,
                                               const float* __restrict__ bk,
                                               const float* __restrict__ bv,
                                               unsigned short* __restrict__ qbf,
                                               unsigned short* __restrict__ kbf,
                                               unsigned short* __restrict__ vbf) {
  int b = blockIdx.x >> 7;
  int nb = blockIdx.x & 127;
  int n0 = nb * 32;
  int tid = threadIdx.x;
  int qr = tid >> 6;                // wave id = output quarter
  int lane = tid & 63;
  int l15 = lane & 15, quad = lane >> 4;

  // xs[n_local][c] bf16, row stride 264 shorts (16B-aligned)
  __shared__ alignas(16) unsigned short xs[32][264];
  __shared__ alignas(16) unsigned short Os[4][64][24];

  // ---- stage x -> LDS, coalesced: thread (r0 = tid>>3, g = tid&7) reads
  //      row (pass*32 + r0), cols n0 + g*4 .. +3. Wave = 8 rows x 128B contiguous.
  {
    int g = tid & 7;
    int r0 = tid >> 3;              // 0..31
    const float* xcol = x + (size_t)b * 256 * 4096 + n0 + g * 4;
#pragma unroll
    for (int pass = 0; pass < 8; ++pass) {
      int r = pass * 32 + r0;       // channel 0..255
      float4 d = *(const float4*)(xcol + (size_t)r * 4096);
      xs[g * 4 + 0][r] = f2bf(d.x);
      xs[g * 4 + 1][r] = f2bf(d.y);
      xs[g * 4 + 2][r] = f2bf(d.z);
      xs[g * 4 + 3][r] = f2bf(d.w);
    }
  }
  __syncthreads();

  // ---- two 16-n subtiles (ms = kk half), same verified quarter-tile body ----
#pragma unroll
  for (int ms = 0; ms < 2; ++ms) {
    int m0 = n0 + ms * 16;

    floatx4 acc[5];
#pragma unroll
    for (int tt = 0; tt < 5; ++tt) acc[tt] = floatx4{0.f, 0.f, 0.f, 0.f};

#pragma unroll
    for (int ks = 0; ks < 8; ++ks) {
      bf16x8 a = *(const bf16x8*)&xs[ms * 16 + l15][ks * 32 + quad * 8];
      {
        bf16x8 w = *(const bf16x8*)(Wall + (size_t)(qr * 16 + l15) * 256 + ks * 32 + quad * 8);
        acc[0] = MFMA(a, w, acc[0]);
      }
#pragma unroll
      for (int t = 0; t < 4; ++t) {
        int gt = 4 + qr * 4 + t;
        bf16x8 w = *(const bf16x8*)(Wall + (size_t)(gt * 16 + l15) * 256 + ks * 32 + quad * 8);
        acc[1 + t] = MFMA(a, w, acc[1 + t]);
      }
    }
    // qk tile: o = qr*16 + l15; q (o<32, scaled by log2e) or k. Fragment-linear stores.
    {
      int o = qr * 16 + l15;
      float bias = (o < 32) ? bq[o] : bk[o - 32];
      float scale = (o < 32) ? 1.44269504088896340736f : 1.0f;
      unsigned short* dst = (o < 32) ? qbf : kbf;
      int oc = o & 31;
      int kh = oc >> 4, h2 = (oc >> 3) & 1, c8 = oc & 7;
#pragma unroll
      for (int r = 0; r < 4; ++r) {
        int m = m0 + quad * 4 + r;
        dst[(size_t)b * 131072 + (size_t)(m >> 5) * 1024 + kh * 512 + h2 * 256 +
            (m & 31) * 8 + c8] = f2bf((acc[0][r] + bias) * scale);
      }
    }
    // v tiles (4 -> 64 channels): per-wave LDS transpose then fragment-linear stores
#pragma unroll
    for (int t = 0; t < 4; ++t) {
      int lr = t * 16 + l15;                  // local channel 0..63
      int c = qr * 64 + lr;                   // global v channel
      float bias = bv[c];
#pragma unroll
      for (int r = 0; r < 4; ++r)
        Os[qr][lr][quad * 4 + r] = f2bf(acc[1 + t][r] + bias);
    }
    // Os[qr] is produced and consumed by this wave only -> ds ops are in-order
    // within the wave (compiler inserts lgkmcnt); no block barrier needed.
    {
      int kb = nb, kk = ms;                   // this subtile = one kk-half of key-block nb
#pragma unroll
      for (int i = 0; i < 2; ++i) {
        int idx = lane + 64 * i;              // 128 granules of 16B per wave
        int r = idx >> 1, g = idx & 1;        // r = local ch 0..63, g = hi half
        int c = qr * 64 + r;
        int cb = c >> 5, ch = c & 31;
        *(uint4*)(vbf + (size_t)b * 1048576 + (size_t)kb * 8192 +
                  (size_t)cb * 1024 + kk * 512 + g * 256 + ch * 8) =
            *(const uint4*)&Os[qr][r][g * 8];
      }
    }
  }
}

// ---------- softmax helper: st (16 f32, S^T tile) -> l partial + PV A-fragments ----------
// st reg r holds S^T[key=(r&3)+8*(r>>2)+4*hi][q=lane&31] (32x32 C/D layout).
// S was pre-scaled by log2e (folded into Q), so exp(S) == exp2(st).
// pa[ks] must hold P[q=lane&31][key=16*ks+8*hi+j], j=0..7 (32x32 A-operand layout).
__device__ __forceinline__ void softmax_pack(floatx16 st, float& lp, bf16x8 (&pa)[2], int hi) {
  float p[16];
#pragma unroll
  for (int r = 0; r < 16; ++r) p[r] = exp2_fast(st[r]);
  lp += (((p[0] + p[1]) + (p[2] + p[3])) + ((p[4] + p[5]) + (p[6] + p[7]))) +
        (((p[8] + p[9]) + (p[10] + p[11])) + ((p[12] + p[13]) + (p[14] + p[15])));
  unsigned d0[4], d1[4];
#pragma unroll
  for (int t = 0; t < 4; ++t) {
    d0[t] = pack2(p[4 * t + 0], p[4 * t + 1]);   // keys r=0,1 of subtile t (own hi)
    d1[t] = pack2(p[4 * t + 2], p[4 * t + 3]);   // keys r=2,3
  }
#pragma unroll
  for (int ks = 0; ks < 2; ++ks) {
#if __has_builtin(__builtin_amdgcn_permlane32_swap)
    (void)hi;
    u32x2 r0 = __builtin_amdgcn_permlane32_swap(d0[2 * ks], d0[2 * ks + 1], false, false);
    u32x2 r1 = __builtin_amdgcn_permlane32_swap(d1[2 * ks], d1[2 * ks + 1], false, false);
    union { unsigned u[4]; bf16x8 v; } u;
    u.u[0] = r0[0]; u.u[1] = r1[0]; u.u[2] = r0[1]; u.u[3] = r1[1];
    pa[ks] = u.v;
#else
    unsigned s0 = hi ? d0[2 * ks] : d0[2 * ks + 1];
    unsigned s1 = hi ? d1[2 * ks] : d1[2 * ks + 1];
    unsigned o0 = (unsigned)__shfl_xor((int)s0, 32);
    unsigned o1 = (unsigned)__shfl_xor((int)s1, 32);
    union { unsigned u[4]; bf16x8 v; } u;
    u.u[0] = hi ? o0 : d0[2 * ks];
    u.u[1] = hi ? o1 : d1[2 * ks];
    u.u[2] = hi ? d0[2 * ks + 1] : o0;
    u.u[3] = hi ? d1[2 * ks + 1] : o1;
    pa[ks] = u.v;
#endif
  }
}

// ---------- K_attn v9 (round-12 best, verbatim): 4-wave blocks + fused merge ----------
// Main loop per wave = v5 (64q x 128ch, barrier-free, in-register softmax).
// Block = (b, cw, qb) with 4 waves, one per key-split s; LDS epilogue reduces the
// 4 splits' (O_s, l_s) in-block and writes out = x + gamma * sumO / suml directly.
// grid = 512 = b(4) x cw(2) x qb(64); XCD-swizzled: XCD x owns one (b,cw) V-set (1MB).
__global__ __launch_bounds__(256, 2) void k_attn(const unsigned short* __restrict__ qbf,
                                                 const unsigned short* __restrict__ kbf,
                                                 const unsigned short* __restrict__ vbf,
                                                 const float* __restrict__ x,
                                                 const float* __restrict__ gma,
                                                 float* __restrict__ out) {
  // XCD swizzle: nwg=512, 8 XCDs -> XCD x owns decoded range [x*64, x*64+64)
  int wg = (blockIdx.x & 7) * 64 + (blockIdx.x >> 3);
  const int qb = wg & 63;
  const int g  = wg >> 6;
  const int cw = g & 1;
  const int b  = g >> 1;
  const int s  = threadIdx.x >> 6;          // wave id = key-split
  const int lane = threadIdx.x & 63;
  const int l31 = lane & 31;
  const int hi  = lane >> 5;
  const int q0  = qb * 64;

  __shared__ float lpL[4][64];
  __shared__ float ltot[64];
  __shared__ alignas(16) unsigned short Ol[4][128][40];   // padded rows (80B) for banks

  const floatx16 z16 = {0.f, 0.f, 0.f, 0.f, 0.f, 0.f, 0.f, 0.f,
                        0.f, 0.f, 0.f, 0.f, 0.f, 0.f, 0.f, 0.f};

  // Q fragments (B-operand: col = query l31, row ch = kh*16 + hi*8 + j), hoisted.
  bf16x8 qf[2][2];
  {
    const unsigned short* qbase =
        qbf + (size_t)b * 131072 + (size_t)(qb * 2) * 1024 + hi * 256 + l31 * 8;
#pragma unroll
    for (int qs2 = 0; qs2 < 2; ++qs2)
#pragma unroll
      for (int kh = 0; kh < 2; ++kh)
        qf[qs2][kh] = *(const bf16x8*)(qbase + qs2 * 1024 + kh * 512);
  }

  floatx16 acc[2][4];
#pragma unroll
  for (int i = 0; i < 2; ++i)
#pragma unroll
    for (int j = 0; j < 4; ++j) acc[i][j] = z16;

  float lp0 = 0.f, lp1 = 0.f;

  // K fragment base (A-operand: row = key l31, ch = kh*16 + hi*8 + j)
  const unsigned short* krow =
      kbf + (size_t)b * 131072 + (size_t)(s * 32) * 1024 + hi * 256 + l31 * 8;
  // V fragment base (B-operand: col = channel l31, key = kk*16 + hi*8 + j)
  const unsigned short* vrow =
      vbf + (size_t)b * 1048576 + (size_t)(s * 32) * 8192 + (size_t)(cw * 4) * 1024 +
      hi * 256 + l31 * 8;

  // ---- prologue: ST(0), then load K(1) into the single K buffer ----
  bf16x8 kf0 = *(const bf16x8*)krow;
  bf16x8 kf1 = *(const bf16x8*)(krow + 512);
  floatx16 st0 = MFMA32(kf0, qf[0][0], z16);
  st0 = MFMA32(kf1, qf[0][1], st0);
  floatx16 st1 = MFMA32(kf0, qf[1][0], z16);
  st1 = MFMA32(kf1, qf[1][1], st1);
  kf0 = *(const bf16x8*)(krow + 1024);
  kf1 = *(const bf16x8*)(krow + 1024 + 512);

  for (int it = 0; it < 32; ++it) {
    // ---- V loads first: consumed at PV (softmax + ST issue in between)
    bf16x8 vb[4][2];
    const unsigned short* vit = vrow + (size_t)it * 8192;
#pragma unroll
    for (int ct = 0; ct < 4; ++ct) {
      vb[ct][0] = *(const bf16x8*)(vit + ct * 1024);
      vb[ct][1] = *(const bf16x8*)(vit + ct * 1024 + 512);
    }

    // ---- softmax on st = S^T(it), computed LAST iteration -> no wait ----
    bf16x8 pa[2][2];
    softmax_pack(st0, lp0, pa[0], hi);
    softmax_pack(st1, lp1, pa[1], hi);

    // ---- ST(it+1): reuses st regs; kf holds K(it+1). Wrapped last iter -> dead compute.
    st0 = MFMA32(kf0, qf[0][0], z16);
    st0 = MFMA32(kf1, qf[0][1], st0);
    st1 = MFMA32(kf0, qf[1][0], z16);
    st1 = MFMA32(kf1, qf[1][1], st1);

    // ---- K(it+2) load (consumed next iter's ST; wrapped index in-region) ----
    const unsigned short* kn = krow + (size_t)((it + 2) & 31) * 1024;
    kf0 = *(const bf16x8*)kn;
    kf1 = *(const bf16x8*)(kn + 512);

    // ---- PV(it): 16 MFMAs, V frags reused across both query subtiles ----
    __builtin_amdgcn_s_setprio(1);
#pragma unroll
    for (int ct = 0; ct < 4; ++ct) {
      acc[0][ct] = MFMA32(pa[0][0], vb[ct][0], acc[0][ct]);
      acc[1][ct] = MFMA32(pa[1][0], vb[ct][0], acc[1][ct]);
      acc[0][ct] = MFMA32(pa[0][1], vb[ct][1], acc[0][ct]);
      acc[1][ct] = MFMA32(pa[1][1], vb[ct][1], acc[1][ct]);
    }
    __builtin_amdgcn_s_setprio(0);
  }

  // ---- fused cross-split reduction + normalize + residual epilogue ----
  lp0 += __shfl_xor(lp0, 32);
  lp1 += __shfl_xor(lp1, 32);
  lpL[s][hi * 32 + l31] = hi ? lp1 : lp0;   // query q0 + hi*32 + l31
  __syncthreads();
  if (threadIdx.x < 64) {
    int q = threadIdx.x;
    ltot[q] = (lpL[0][q] + lpL[1][q]) + (lpL[2][q] + lpL[3][q]);
  }
  const float gv = gma[0];

#pragma unroll
  for (int qs2 = 0; qs2 < 2; ++qs2) {
    // write this wave's 32q x 128ch partial O (bf16, RNE - same rounding as old Obf)
#pragma unroll
    for (int ct = 0; ct < 4; ++ct) {
#pragma unroll
      for (int gi = 0; gi < 4; ++gi) {
        unsigned w0 = pack2(acc[qs2][ct][4 * gi + 0], acc[qs2][ct][4 * gi + 1]);
        unsigned w1 = pack2(acc[qs2][ct][4 * gi + 2], acc[qs2][ct][4 * gi + 3]);
        unsigned long long w = (unsigned long long)w0 | ((unsigned long long)w1 << 32);
        *(unsigned long long*)&Ol[s][ct * 32 + l31][8 * gi + 4 * hi] = w;
      }
    }
    __syncthreads();   // Ol (and, first pass, ltot) ready
    {
      int ch = threadIdx.x >> 1;            // 0..127
      int qh = threadIdx.x & 1;             // 16-query half
      int qoff = qs2 * 32 + qh * 16;
      float o[16];
#pragma unroll
      for (int j = 0; j < 16; ++j) o[j] = 0.f;
#pragma unroll
      for (int sp = 0; sp < 4; ++sp) {
        const uint4* p = (const uint4*)&Ol[sp][ch][qh * 16];
        uint4 a0 = p[0], a1 = p[1];
        unsigned uu[8] = {a0.x, a0.y, a0.z, a0.w, a1.x, a1.y, a1.z, a1.w};
#pragma unroll
        for (int jj = 0; jj < 8; ++jj) {
          o[2 * jj + 0] += bf2f((unsigned short)(uu[jj] & 0xffffu));
          o[2 * jj + 1] += bf2f((unsigned short)(uu[jj] >> 16));
        }
      }
      size_t rowa = ((size_t)b * 256 + cw * 128 + ch) * 4096 + q0 + qoff;
      const float* xrow = x + rowa;
      float* orow = out + rowa;
#pragma unroll
      for (int j4 = 0; j4 < 4; ++j4) {
        float4 xv = *(const float4*)(xrow + j4 * 4);
        float4 r;
        r.x = xv.x + gv * o[j4 * 4 + 0] / ltot[qoff + j4 * 4 + 0];
        r.y = xv.y + gv * o[j4 * 4 + 1] / ltot[qoff + j4 * 4 + 1];
        r.z = xv.z + gv * o[j4 * 4 + 2] / ltot[qoff + j4 * 4 + 2];
        r.w = xv.w + gv * o[j4 * 4 + 3] / ltot[qoff + j4 * 4 + 3];
        *(float4*)(orow + j4 * 4) = r;
      }
    }
    __syncthreads();   // drain readers before next phase overwrites Ol
  }
}

// ---------- launch ----------
extern "C" void kernel_launch(void* const* d_in, const int* in_sizes, int n_in,
                              void* d_out, int out_size, void* d_ws, size_t ws_size,
                              hipStream_t stream) {
  const float* x   = (const float*)d_in[0];
  const float* Wq  = (const float*)d_in[1];
  const float* bq  = (const float*)d_in[2];
  const float* Wk  = (const float*)d_in[3];
  const float* bk  = (const float*)d_in[4];
  const float* Wv  = (const float*)d_in[5];
  const float* bv  = (const float*)d_in[6];
  const float* gma = (const float*)d_in[7];
  float* out = (float*)d_out;

  // layout: [qbf][kbf][vbf][Wall]
  unsigned short* qbf  = (unsigned short*)d_ws;              // [4][128][2][2][32][8]
  unsigned short* kbf  = qbf + (size_t)4 * 131072;           // [4][128][2][2][32][8]
  unsigned short* vbf  = kbf + (size_t)4 * 131072;           // [4][128][8][2][2][32][8]
  unsigned short* Wall = vbf + (size_t)4 * 1048576;          // [320][256]

  k_wconv<<<320, 256, 0, stream>>>(Wq, Wk, Wv, Wall);
  k_projx<<<512, 256, 0, stream>>>(x, Wall, bq, bk, bv, qbf, kbf, vbf);
  k_attn<<<512, 256, 0, stream>>>(qbf, kbf, vbf, x, gma, out);
}